// Round 3
// baseline (1160.728 us; speedup 1.0000x reference)
//
#include <hip/hip_runtime.h>
#include <hip/hip_bf16.h>

// RWKV7 WKV chunked scan. T=4096, H=32, N=64. Output fp32 (y then S_final).
//
// Pass 1 (rewritten R2): one WAVE per (chunk, head, {P|M}); thread = one row in
//   64 VGPRs. The per-step shared vectors (w,k,a,b,r) are wave-uniform -> read
//   with UNIFORM loads (s_load into SGPRs) instead of LDS broadcast: removes
//   the ~80 ds_read_b128/step that made R1's pass1 LDS-issue bound (392us).
//   No LDS, no barriers. M-variant drops the v*k term (skips k,v entirely).
// Pass 2: sequential chain over 64 chunks: S_c = S_{c-1} M_c + P_c.
// Pass 3: y_t = y_local_t + S_before[c] @ rho_t.

#define Tt 4096
#define Hh 32
#define Nn 64
#define Ll 64              // chunk length
#define Cc 64              // number of chunks
#define HN (Hh * Nn)       // 2048
#define NN (Nn * Nn)       // 4096

__device__ __forceinline__ float ldf(const float* p) { return *p; }
__device__ __forceinline__ float ldf(const __hip_bfloat16* p) { return __bfloat162float(*p); }
__device__ __forceinline__ void stf(float* p, float v) { *p = v; }
__device__ __forceinline__ void stf(__hip_bfloat16* p, float v) { *p = __float2bfloat16(v); }

// ---------------------------------------------------------------- pass 1
// ISM=false: P scan (from 0, with v k^T term), y_local out (fp32).
// ISM=true : M scan (from I, no v k^T),        rho out (ST).
template <bool ISM, typename ST>
__device__ __forceinline__ void scan_chunk(
    int c, int h, int lane,
    const float* __restrict__ rr, const float* __restrict__ ww,
    const float* __restrict__ kk, const float* __restrict__ vv,
    const float* __restrict__ aa, const float* __restrict__ bb,
    float* __restrict__ yf, ST* __restrict__ ys, ST* __restrict__ MPt)
{
    float S[Nn];
    #pragma unroll
    for (int j = 0; j < Nn; ++j) S[j] = ISM ? ((j == lane) ? 1.0f : 0.0f) : 0.0f;

    int base = (c * Ll * Hh + h) * Nn;       // uniform element offset of step t=0
    float vpre = ISM ? 0.0f : vv[base + lane];

    for (int t = 0; t < Ll; ++t) {
        const float4* a4 = (const float4*)(aa + base);   // uniform -> s_load
        const float4* w4 = (const float4*)(ww + base);
        const float4* b4 = (const float4*)(bb + base);
        const float4* r4 = (const float4*)(rr + base);
        const float4* k4 = (const float4*)(kk + base);

        // sa = S_row . a  (pre-update state)
        float s0 = 0.f, s1 = 0.f, s2 = 0.f, s3 = 0.f;
        #pragma unroll
        for (int q = 0; q < 16; ++q) {
            const float4 av = a4[q];
            s0 += S[4 * q + 0] * av.x;
            s1 += S[4 * q + 1] * av.y;
            s2 += S[4 * q + 2] * av.z;
            s3 += S[4 * q + 3] * av.w;
        }
        const float sa = (s0 + s1) + (s2 + s3);

        const float vval = vpre;
        if (!ISM && t + 1 < Ll) vpre = vv[base + HN + lane];   // prefetch next v

        // S = S*w + sa*b (+ v*k) ; y = S_new . r
        float y0 = 0.f, y1 = 0.f, y2 = 0.f, y3 = 0.f;
        #pragma unroll
        for (int q = 0; q < 16; ++q) {
            const float4 wv = w4[q];
            const float4 bv = b4[q];
            const float4 rv = r4[q];
            if (!ISM) {
                const float4 kv = k4[q];
                S[4 * q + 0] = S[4 * q + 0] * wv.x + sa * bv.x + vval * kv.x;
                S[4 * q + 1] = S[4 * q + 1] * wv.y + sa * bv.y + vval * kv.y;
                S[4 * q + 2] = S[4 * q + 2] * wv.z + sa * bv.z + vval * kv.z;
                S[4 * q + 3] = S[4 * q + 3] * wv.w + sa * bv.w + vval * kv.w;
            } else {
                S[4 * q + 0] = S[4 * q + 0] * wv.x + sa * bv.x;
                S[4 * q + 1] = S[4 * q + 1] * wv.y + sa * bv.y;
                S[4 * q + 2] = S[4 * q + 2] * wv.z + sa * bv.z;
                S[4 * q + 3] = S[4 * q + 3] * wv.w + sa * bv.w;
            }
            y0 += S[4 * q + 0] * rv.x;
            y1 += S[4 * q + 1] * rv.y;
            y2 += S[4 * q + 2] * rv.z;
            y3 += S[4 * q + 3] * rv.w;
        }
        const float y = (y0 + y1) + (y2 + y3);
        if (ISM) stf(&ys[base + lane], y);   // rho = M_t r_t
        else     yf[base + lane] = y;        // y_local
        base += HN;
    }

    // chunk-final matrix, stored transposed: [c][h][col j][row lane]
    const size_t mb = ((size_t)(c * Hh) + h) * NN;
    #pragma unroll
    for (int j = 0; j < Nn; ++j) stf(&MPt[mb + (size_t)j * Nn + lane], S[j]);
}

template <typename ST>
__global__ __launch_bounds__(64, 4)
void pass1_scan(const float* __restrict__ rr, const float* __restrict__ ww,
                const float* __restrict__ kk, const float* __restrict__ vv,
                const float* __restrict__ aa, const float* __restrict__ bb,
                float* __restrict__ ylocal,
                ST* __restrict__ rho, ST* __restrict__ Mt, ST* __restrict__ Pt)
{
    const int cz   = blockIdx.x >> 1;      // (c,h) pair index
    const int ism  = blockIdx.x & 1;       // adjacent P/M blocks share inputs (L2/K$)
    const int c    = cz >> 5;              // cz / Hh
    const int h    = cz & 31;              // cz % Hh
    const int lane = threadIdx.x;

    if (ism) scan_chunk<true >(c, h, lane, rr, ww, kk, vv, aa, bb, ylocal, rho, Mt);
    else     scan_chunk<false>(c, h, lane, rr, ww, kk, vv, aa, bb, ylocal, rho, Pt);
}

// ---------------------------------------------------------------- pass 2
template <typename ST>
__global__ __launch_bounds__(256, 1)
void pass2_chain(const ST* __restrict__ Mt, const ST* __restrict__ Pt,
                 const float* __restrict__ st0, ST* __restrict__ Sst,
                 float* __restrict__ sfin)
{
    const int h   = blockIdx.x >> 3;
    const int g   = blockIdx.x & 7;
    const int tid = threadIdx.x;
    const int li  = tid >> 5;          // 0..7 local row
    const int i   = g * 8 + li;        // global row
    const int j2  = (tid & 31) * 2;    // column pair

    __shared__ float Mlds[Nn][Nn + 4]; // [row k][col j]
    __shared__ float Slds[8][Nn + 1];  // [li][col]

    float s0 = st0[(h * Nn + i) * Nn + j2];
    float s1 = st0[(h * Nn + i) * Nn + j2 + 1];
    Slds[li][j2]     = s0;
    Slds[li][j2 + 1] = s1;

    // prefetch chunk 0: Mt flat index lin = col*64 + row; Pt[col*64 + row]
    float mpre[16];
    {
        const size_t mb = (size_t)h * NN;
        #pragma unroll
        for (int q = 0; q < 16; ++q) mpre[q] = ldf(&Mt[mb + (size_t)tid * 16 + q]);
    }
    float pp0 = ldf(&Pt[(size_t)h * NN + (size_t)j2 * Nn + i]);
    float pp1 = ldf(&Pt[(size_t)h * NN + (size_t)(j2 + 1) * Nn + i]);
    __syncthreads();

    for (int c = 0; c < Cc; ++c) {
        // S_before[c] out (row-major [i][j])
        const size_t sb = ((size_t)(c * Hh) + h) * NN;
        stf(&Sst[sb + (size_t)i * Nn + j2],     s0);
        stf(&Sst[sb + (size_t)i * Nn + j2 + 1], s1);

        // un-transpose prefetched Mt into Mlds[row][col]
        #pragma unroll
        for (int q = 0; q < 16; ++q) {
            const int lin = tid * 16 + q;          // lin = col*64 + row
            Mlds[lin & 63][lin >> 6] = mpre[q];
        }
        __syncthreads();

        float np0 = 0.f, np1 = 0.f;
        if (c + 1 < Cc) {                          // prefetch next chunk during k-loop
            const size_t mb2 = ((size_t)((c + 1) * Hh) + h) * NN;
            #pragma unroll
            for (int q = 0; q < 16; ++q) mpre[q] = ldf(&Mt[mb2 + (size_t)tid * 16 + q]);
            np0 = ldf(&Pt[mb2 + (size_t)j2 * Nn + i]);
            np1 = ldf(&Pt[mb2 + (size_t)(j2 + 1) * Nn + i]);
        }

        // newS[i][j] = sum_k S[i][k] * M[k][j] + P[i][j]
        float a0 = pp0, b0 = 0.f, a1 = pp1, b1 = 0.f;
        #pragma unroll
        for (int kq = 0; kq < Nn; kq += 2) {
            const float se = Slds[li][kq];
            const float so = Slds[li][kq + 1];
            a0 += se * Mlds[kq][j2];
            b0 += so * Mlds[kq + 1][j2];
            a1 += se * Mlds[kq][j2 + 1];
            b1 += so * Mlds[kq + 1][j2 + 1];
        }
        const float acc0 = a0 + b0, acc1 = a1 + b1;
        __syncthreads();
        Slds[li][j2]     = acc0;
        Slds[li][j2 + 1] = acc1;
        s0 = acc0; s1 = acc1;
        pp0 = np0; pp1 = np1;
        __syncthreads();
    }

    // final state -> d_out tail (fp32)
    sfin[(h * Nn + i) * Nn + j2]     = s0;
    sfin[(h * Nn + i) * Nn + j2 + 1] = s1;
}

// ---------------------------------------------------------------- pass 3
template <typename ST>
__global__ __launch_bounds__(256, 4)
void pass3_fix(const ST* __restrict__ rho, const ST* __restrict__ Sst,
               float* __restrict__ y)
{
    const int c    = blockIdx.x / Hh;
    const int h    = blockIdx.x % Hh;
    const int tid  = threadIdx.x;
    const int lane = tid & 63;   // output row i
    const int tq   = tid >> 6;   // 0..3

    __shared__ float Rlds[Ll][Nn];   // rho rows for this chunk

    {
        const int tl = tid >> 2;
        const int j0 = (tid & 3) * 16;
        const int gb = ((c * Ll + tl) * Hh + h) * Nn + j0;
        #pragma unroll
        for (int q = 0; q < 16; ++q) Rlds[tl][j0 + q] = ldf(&rho[gb + q]);
    }

    float Srow[Nn];  // S_before[c][h] row `lane`
    {
        const size_t sb = ((size_t)(c * Hh) + h) * NN + (size_t)lane * Nn;
        #pragma unroll
        for (int j = 0; j < Nn; ++j) Srow[j] = ldf(&Sst[sb + j]);
    }
    __syncthreads();

    for (int m = 0; m < 16; ++m) {
        const int tl = tq + m * 4;
        float a0 = 0.f, a1 = 0.f, a2 = 0.f, a3 = 0.f;
        #pragma unroll
        for (int j = 0; j < Nn; j += 4) {
            a0 += Srow[j + 0] * Rlds[tl][j + 0];
            a1 += Srow[j + 1] * Rlds[tl][j + 1];
            a2 += Srow[j + 2] * Rlds[tl][j + 2];
            a3 += Srow[j + 3] * Rlds[tl][j + 3];
        }
        const int oy = ((c * Ll + tl) * Hh + h) * Nn + lane;
        y[oy] = y[oy] + ((a0 + a1) + (a2 + a3));
    }
}

// ------------------------------------------- zero-scratch sequential fallback
__global__ __launch_bounds__(64, 1)
void seq_scan(const float* __restrict__ rr, const float* __restrict__ ww,
              const float* __restrict__ kk, const float* __restrict__ vv,
              const float* __restrict__ aa, const float* __restrict__ bb,
              const float* __restrict__ st0,
              float* __restrict__ y, float* __restrict__ sfin)
{
    const int h    = blockIdx.x;
    const int lane = threadIdx.x;          // row i

    float S[Nn];
    #pragma unroll
    for (int j = 0; j < Nn; ++j) S[j] = st0[(h * Nn + lane) * Nn + j];

    int base = h * Nn;
    for (int t = 0; t < Tt; ++t) {
        const float4* a4 = (const float4*)(aa + base);
        const float4* w4 = (const float4*)(ww + base);
        const float4* b4 = (const float4*)(bb + base);
        const float4* r4 = (const float4*)(rr + base);
        const float4* k4 = (const float4*)(kk + base);
        const float vval = vv[base + lane];

        float sa = 0.f;
        #pragma unroll
        for (int q = 0; q < 16; ++q) {
            const float4 av = a4[q];
            sa += S[4 * q + 0] * av.x + S[4 * q + 1] * av.y
                + S[4 * q + 2] * av.z + S[4 * q + 3] * av.w;
        }

        float yv = 0.f;
        #pragma unroll
        for (int q = 0; q < 16; ++q) {
            const float4 wv = w4[q];
            const float4 bv = b4[q];
            const float4 rv = r4[q];
            const float4 kv = k4[q];
            S[4 * q + 0] = S[4 * q + 0] * wv.x + sa * bv.x + vval * kv.x;
            S[4 * q + 1] = S[4 * q + 1] * wv.y + sa * bv.y + vval * kv.y;
            S[4 * q + 2] = S[4 * q + 2] * wv.z + sa * bv.z + vval * kv.z;
            S[4 * q + 3] = S[4 * q + 3] * wv.w + sa * bv.w + vval * kv.w;
            yv += S[4 * q + 0] * rv.x + S[4 * q + 1] * rv.y
                + S[4 * q + 2] * rv.z + S[4 * q + 3] * rv.w;
        }
        y[base + lane] = yv;
        base += HN;
    }

    #pragma unroll
    for (int j = 0; j < Nn; ++j) sfin[(h * Nn + lane) * Nn + j] = S[j];
}

// ---------------------------------------------------------------- launch
extern "C" void kernel_launch(void* const* d_in, const int* in_sizes, int n_in,
                              void* d_out, int out_size, void* d_ws, size_t ws_size,
                              hipStream_t stream)
{
    const float* r  = (const float*)d_in[0];
    const float* w  = (const float*)d_in[1];
    const float* k  = (const float*)d_in[2];
    const float* v  = (const float*)d_in[3];
    const float* a  = (const float*)d_in[4];
    const float* b  = (const float*)d_in[5];
    const float* st = (const float*)d_in[6];

    float* out  = (float*)d_out;
    float* yl   = out;                       // y region (also y_local scratch)
    float* sfin = out + (size_t)Tt * HN;     // S_final region

    const size_t nTHN = (size_t)Tt * HN;       // 8388608 (rho)
    const size_t nCH  = (size_t)Cc * Hh * NN;  // 8388608 (each of Mt, Pt, Sst)
    const size_t need = nTHN + 3 * nCH;        // scratch element count

    if (ws_size >= need * sizeof(float)) {
        float* ws  = (float*)d_ws;
        float* rho = ws;
        float* Mt  = ws + nTHN;
        float* Pt  = Mt + nCH;
        float* Ss  = Pt + nCH;
        hipLaunchKernelGGL((pass1_scan<float>), dim3(2 * Cc * Hh), dim3(64), 0, stream,
                           r, w, k, v, a, b, yl, rho, Mt, Pt);
        hipLaunchKernelGGL((pass2_chain<float>), dim3(Hh * 8), dim3(256), 0, stream,
                           Mt, Pt, st, Ss, sfin);
        hipLaunchKernelGGL((pass3_fix<float>), dim3(Cc * Hh), dim3(256), 0, stream,
                           rho, Ss, out);
    } else if (ws_size >= need * sizeof(__hip_bfloat16)) {
        __hip_bfloat16* ws  = (__hip_bfloat16*)d_ws;
        __hip_bfloat16* rho = ws;
        __hip_bfloat16* Mt  = ws + nTHN;
        __hip_bfloat16* Pt  = Mt + nCH;
        __hip_bfloat16* Ss  = Pt + nCH;
        hipLaunchKernelGGL((pass1_scan<__hip_bfloat16>), dim3(2 * Cc * Hh), dim3(64), 0, stream,
                           r, w, k, v, a, b, yl, rho, Mt, Pt);
        hipLaunchKernelGGL((pass2_chain<__hip_bfloat16>), dim3(Hh * 8), dim3(256), 0, stream,
                           Mt, Pt, st, Ss, sfin);
        hipLaunchKernelGGL((pass3_fix<__hip_bfloat16>), dim3(Cc * Hh), dim3(256), 0, stream,
                           rho, Ss, out);
    } else {
        // no usable scratch: correct-but-slow sequential scan
        hipLaunchKernelGGL(seq_scan, dim3(Hh), dim3(64), 0, stream,
                           r, w, k, v, a, b, st, yl, sfin);
    }
}

// Round 4
// 751.672 us; speedup vs baseline: 1.5442x; 1.5442x over previous
//
#include <hip/hip_runtime.h>
#include <hip/hip_bf16.h>

// RWKV7 WKV chunked scan. T=4096, H=32, N=64. Output fp32 (y then S_final).
//
// Pass 1 (R4): ONE wave per (chunk, head), computing BOTH the P scan (from 0,
//   with v k^T term; emits y_local) and the M scan (from I; emits rho) fused.
//   Lane = row; S_P + S_M = 128 VGPRs. The 5 shared per-step vectors
//   (w,a,b,r,k) are loaded coalesced (lane j holds elem j, prefetched one step
//   ahead) and broadcast with v_readlane on the VALU pipe — no LDS (R1 was
//   LDS-issue bound at 392us), no scalar-cache latency chain (R2 regression).
//   Fusion shares every broadcast between the two scans.
// Pass 2: sequential chain over 64 chunks: S_c = S_{c-1} M_c + P_c.
// Pass 3: y_t = y_local_t + S_before[c] @ rho_t.

#define Tt 4096
#define Hh 32
#define Nn 64
#define Ll 64              // chunk length
#define Cc 64              // number of chunks
#define HN (Hh * Nn)       // 2048
#define NN (Nn * Nn)       // 4096

__device__ __forceinline__ float ldf(const float* p) { return *p; }
__device__ __forceinline__ float ldf(const __hip_bfloat16* p) { return __bfloat162float(*p); }
__device__ __forceinline__ void stf(float* p, float v) { *p = v; }
__device__ __forceinline__ void stf(__hip_bfloat16* p, float v) { *p = __float2bfloat16(v); }

__device__ __forceinline__ float rl(float v, int j) {
    return __int_as_float(__builtin_amdgcn_readlane(__float_as_int(v), j));
}

// ---------------------------------------------------------------- pass 1
template <typename ST>
__global__ __launch_bounds__(64, 2)
void pass1_scan(const float* __restrict__ rr, const float* __restrict__ ww,
                const float* __restrict__ kk, const float* __restrict__ vv,
                const float* __restrict__ aa, const float* __restrict__ bb,
                float* __restrict__ ylocal,
                ST* __restrict__ rho, ST* __restrict__ Mt, ST* __restrict__ Pt)
{
    const int c    = blockIdx.x >> 5;      // chunk
    const int h    = blockIdx.x & 31;      // head
    const int lane = threadIdx.x;          // row i

    float SP[Nn];                          // P scan state (row `lane`)
    float SM[Nn];                          // M scan state (row `lane`)
    #pragma unroll
    for (int j = 0; j < Nn; ++j) {
        SP[j] = 0.0f;
        SM[j] = (j == lane) ? 1.0f : 0.0f;
    }

    int base = (c * Ll * Hh + h) * Nn;     // element offset of step t
    // current step's vectors, lane-distributed (lane j holds element j)
    float ca = aa[base + lane];
    float cw = ww[base + lane];
    float cb = bb[base + lane];
    float cr = rr[base + lane];
    float ck = kk[base + lane];
    float cv = vv[base + lane];            // per-lane (row) value, not broadcast

    for (int t = 0; t < Ll; ++t) {
        // prefetch next step's vectors (uniform branch)
        float na = 0.f, nw = 0.f, nb = 0.f, nr = 0.f, nk = 0.f, nv = 0.f;
        if (t + 1 < Ll) {
            const int b2 = base + HN + lane;
            na = aa[b2]; nw = ww[b2]; nb = bb[b2];
            nr = rr[b2]; nk = kk[b2]; nv = vv[b2];
        }

        // sa = S_row . a  for both scans (shared a broadcasts)
        float p0 = 0.f, p1 = 0.f, p2 = 0.f, p3 = 0.f;
        float m0 = 0.f, m1 = 0.f, m2 = 0.f, m3 = 0.f;
        #pragma unroll
        for (int j = 0; j < Nn; j += 4) {
            const float a0 = rl(ca, j + 0), a1 = rl(ca, j + 1);
            const float a2 = rl(ca, j + 2), a3 = rl(ca, j + 3);
            p0 += SP[j + 0] * a0;  m0 += SM[j + 0] * a0;
            p1 += SP[j + 1] * a1;  m1 += SM[j + 1] * a1;
            p2 += SP[j + 2] * a2;  m2 += SM[j + 2] * a2;
            p3 += SP[j + 3] * a3;  m3 += SM[j + 3] * a3;
        }
        const float saP = (p0 + p1) + (p2 + p3);
        const float saM = (m0 + m1) + (m2 + m3);

        // S = S*w + sa*b (+ v*k) ; y = S_P.r ; q = S_M.r  (shared w,b,k,r broadcasts)
        float y0 = 0.f, y1 = 0.f, q0 = 0.f, q1 = 0.f;
        #pragma unroll
        for (int j = 0; j < Nn; j += 2) {
            const float w0 = rl(cw, j), w1 = rl(cw, j + 1);
            const float b0 = rl(cb, j), b1 = rl(cb, j + 1);
            const float k0 = rl(ck, j), k1 = rl(ck, j + 1);
            const float r0 = rl(cr, j), r1 = rl(cr, j + 1);
            SP[j + 0] = SP[j + 0] * w0 + saP * b0 + cv * k0;
            SP[j + 1] = SP[j + 1] * w1 + saP * b1 + cv * k1;
            SM[j + 0] = SM[j + 0] * w0 + saM * b0;
            SM[j + 1] = SM[j + 1] * w1 + saM * b1;
            y0 += SP[j + 0] * r0;
            y1 += SP[j + 1] * r1;
            q0 += SM[j + 0] * r0;
            q1 += SM[j + 1] * r1;
        }
        ylocal[base + lane] = y0 + y1;          // y_local = P_t r_t
        stf(&rho[base + lane], q0 + q1);        // rho     = M_t r_t

        base += HN;
        ca = na; cw = nw; cb = nb; cr = nr; ck = nk; cv = nv;
    }

    // chunk-final matrices, stored transposed: [c][h][col j][row lane]
    const size_t mb = ((size_t)(c * Hh) + h) * NN;
    #pragma unroll
    for (int j = 0; j < Nn; ++j) {
        stf(&Pt[mb + (size_t)j * Nn + lane], SP[j]);
        stf(&Mt[mb + (size_t)j * Nn + lane], SM[j]);
    }
}

// ---------------------------------------------------------------- pass 2
template <typename ST>
__global__ __launch_bounds__(256, 1)
void pass2_chain(const ST* __restrict__ Mt, const ST* __restrict__ Pt,
                 const float* __restrict__ st0, ST* __restrict__ Sst,
                 float* __restrict__ sfin)
{
    const int h   = blockIdx.x >> 3;
    const int g   = blockIdx.x & 7;
    const int tid = threadIdx.x;
    const int li  = tid >> 5;          // 0..7 local row
    const int i   = g * 8 + li;        // global row
    const int j2  = (tid & 31) * 2;    // column pair

    __shared__ float Mlds[Nn][Nn + 4]; // [row k][col j]
    __shared__ float Slds[8][Nn + 1];  // [li][col]

    float s0 = st0[(h * Nn + i) * Nn + j2];
    float s1 = st0[(h * Nn + i) * Nn + j2 + 1];
    Slds[li][j2]     = s0;
    Slds[li][j2 + 1] = s1;

    // prefetch chunk 0: Mt flat index lin = col*64 + row; Pt[col*64 + row]
    float mpre[16];
    {
        const size_t mb = (size_t)h * NN;
        #pragma unroll
        for (int q = 0; q < 16; ++q) mpre[q] = ldf(&Mt[mb + (size_t)tid * 16 + q]);
    }
    float pp0 = ldf(&Pt[(size_t)h * NN + (size_t)j2 * Nn + i]);
    float pp1 = ldf(&Pt[(size_t)h * NN + (size_t)(j2 + 1) * Nn + i]);
    __syncthreads();

    for (int c = 0; c < Cc; ++c) {
        // S_before[c] out (row-major [i][j])
        const size_t sb = ((size_t)(c * Hh) + h) * NN;
        stf(&Sst[sb + (size_t)i * Nn + j2],     s0);
        stf(&Sst[sb + (size_t)i * Nn + j2 + 1], s1);

        // un-transpose prefetched Mt into Mlds[row][col]
        #pragma unroll
        for (int q = 0; q < 16; ++q) {
            const int lin = tid * 16 + q;          // lin = col*64 + row
            Mlds[lin & 63][lin >> 6] = mpre[q];
        }
        __syncthreads();

        float np0 = 0.f, np1 = 0.f;
        if (c + 1 < Cc) {                          // prefetch next chunk during k-loop
            const size_t mb2 = ((size_t)((c + 1) * Hh) + h) * NN;
            #pragma unroll
            for (int q = 0; q < 16; ++q) mpre[q] = ldf(&Mt[mb2 + (size_t)tid * 16 + q]);
            np0 = ldf(&Pt[mb2 + (size_t)j2 * Nn + i]);
            np1 = ldf(&Pt[mb2 + (size_t)(j2 + 1) * Nn + i]);
        }

        // newS[i][j] = sum_k S[i][k] * M[k][j] + P[i][j]
        float a0 = pp0, b0 = 0.f, a1 = pp1, b1 = 0.f;
        #pragma unroll
        for (int kq = 0; kq < Nn; kq += 2) {
            const float se = Slds[li][kq];
            const float so = Slds[li][kq + 1];
            a0 += se * Mlds[kq][j2];
            b0 += so * Mlds[kq + 1][j2];
            a1 += se * Mlds[kq][j2 + 1];
            b1 += so * Mlds[kq + 1][j2 + 1];
        }
        const float acc0 = a0 + b0, acc1 = a1 + b1;
        __syncthreads();
        Slds[li][j2]     = acc0;
        Slds[li][j2 + 1] = acc1;
        s0 = acc0; s1 = acc1;
        pp0 = np0; pp1 = np1;
        __syncthreads();
    }

    // final state -> d_out tail (fp32)
    sfin[(h * Nn + i) * Nn + j2]     = s0;
    sfin[(h * Nn + i) * Nn + j2 + 1] = s1;
}

// ---------------------------------------------------------------- pass 3
template <typename ST>
__global__ __launch_bounds__(256, 4)
void pass3_fix(const ST* __restrict__ rho, const ST* __restrict__ Sst,
               float* __restrict__ y)
{
    const int c    = blockIdx.x / Hh;
    const int h    = blockIdx.x % Hh;
    const int tid  = threadIdx.x;
    const int lane = tid & 63;   // output row i
    const int tq   = tid >> 6;   // 0..3

    __shared__ float Rlds[Ll][Nn];   // rho rows for this chunk

    {
        const int tl = tid >> 2;
        const int j0 = (tid & 3) * 16;
        const int gb = ((c * Ll + tl) * Hh + h) * Nn + j0;
        #pragma unroll
        for (int q = 0; q < 16; ++q) Rlds[tl][j0 + q] = ldf(&rho[gb + q]);
    }

    float Srow[Nn];  // S_before[c][h] row `lane`
    {
        const size_t sb = ((size_t)(c * Hh) + h) * NN + (size_t)lane * Nn;
        #pragma unroll
        for (int j = 0; j < Nn; ++j) Srow[j] = ldf(&Sst[sb + j]);
    }
    __syncthreads();

    for (int m = 0; m < 16; ++m) {
        const int tl = tq + m * 4;
        float a0 = 0.f, a1 = 0.f, a2 = 0.f, a3 = 0.f;
        #pragma unroll
        for (int j = 0; j < Nn; j += 4) {
            a0 += Srow[j + 0] * Rlds[tl][j + 0];
            a1 += Srow[j + 1] * Rlds[tl][j + 1];
            a2 += Srow[j + 2] * Rlds[tl][j + 2];
            a3 += Srow[j + 3] * Rlds[tl][j + 3];
        }
        const int oy = ((c * Ll + tl) * Hh + h) * Nn + lane;
        y[oy] = y[oy] + ((a0 + a1) + (a2 + a3));
    }
}

// ------------------------------------------- zero-scratch sequential fallback
__global__ __launch_bounds__(64, 1)
void seq_scan(const float* __restrict__ rr, const float* __restrict__ ww,
              const float* __restrict__ kk, const float* __restrict__ vv,
              const float* __restrict__ aa, const float* __restrict__ bb,
              const float* __restrict__ st0,
              float* __restrict__ y, float* __restrict__ sfin)
{
    const int h    = blockIdx.x;
    const int lane = threadIdx.x;          // row i

    float S[Nn];
    #pragma unroll
    for (int j = 0; j < Nn; ++j) S[j] = st0[(h * Nn + lane) * Nn + j];

    int base = h * Nn;
    float ca = aa[base + lane], cw = ww[base + lane], cb = bb[base + lane];
    float cr = rr[base + lane], ck = kk[base + lane], cv = vv[base + lane];

    for (int t = 0; t < Tt; ++t) {
        float na = 0.f, nw = 0.f, nb = 0.f, nr = 0.f, nk = 0.f, nv = 0.f;
        if (t + 1 < Tt) {
            const int b2 = base + HN + lane;
            na = aa[b2]; nw = ww[b2]; nb = bb[b2];
            nr = rr[b2]; nk = kk[b2]; nv = vv[b2];
        }

        float s0 = 0.f, s1 = 0.f;
        #pragma unroll
        for (int j = 0; j < Nn; j += 2) {
            s0 += S[j + 0] * rl(ca, j);
            s1 += S[j + 1] * rl(ca, j + 1);
        }
        const float sa = s0 + s1;

        float y0 = 0.f, y1 = 0.f;
        #pragma unroll
        for (int j = 0; j < Nn; j += 2) {
            const float w0 = rl(cw, j), w1 = rl(cw, j + 1);
            const float b0 = rl(cb, j), b1 = rl(cb, j + 1);
            const float k0 = rl(ck, j), k1 = rl(ck, j + 1);
            const float r0 = rl(cr, j), r1 = rl(cr, j + 1);
            S[j + 0] = S[j + 0] * w0 + sa * b0 + cv * k0;
            S[j + 1] = S[j + 1] * w1 + sa * b1 + cv * k1;
            y0 += S[j + 0] * r0;
            y1 += S[j + 1] * r1;
        }
        y[base + lane] = y0 + y1;
        base += HN;
        ca = na; cw = nw; cb = nb; cr = nr; ck = nk; cv = nv;
    }

    #pragma unroll
    for (int j = 0; j < Nn; ++j) sfin[(h * Nn + lane) * Nn + j] = S[j];
}

// ---------------------------------------------------------------- launch
extern "C" void kernel_launch(void* const* d_in, const int* in_sizes, int n_in,
                              void* d_out, int out_size, void* d_ws, size_t ws_size,
                              hipStream_t stream)
{
    const float* r  = (const float*)d_in[0];
    const float* w  = (const float*)d_in[1];
    const float* k  = (const float*)d_in[2];
    const float* v  = (const float*)d_in[3];
    const float* a  = (const float*)d_in[4];
    const float* b  = (const float*)d_in[5];
    const float* st = (const float*)d_in[6];

    float* out  = (float*)d_out;
    float* yl   = out;                       // y region (also y_local scratch)
    float* sfin = out + (size_t)Tt * HN;     // S_final region

    const size_t nTHN = (size_t)Tt * HN;       // 8388608 (rho)
    const size_t nCH  = (size_t)Cc * Hh * NN;  // 8388608 (each of Mt, Pt, Sst)
    const size_t need = nTHN + 3 * nCH;        // scratch element count

    if (ws_size >= need * sizeof(float)) {
        float* ws  = (float*)d_ws;
        float* rho = ws;
        float* Mt  = ws + nTHN;
        float* Pt  = Mt + nCH;
        float* Ss  = Pt + nCH;
        hipLaunchKernelGGL((pass1_scan<float>), dim3(Cc * Hh), dim3(64), 0, stream,
                           r, w, k, v, a, b, yl, rho, Mt, Pt);
        hipLaunchKernelGGL((pass2_chain<float>), dim3(Hh * 8), dim3(256), 0, stream,
                           Mt, Pt, st, Ss, sfin);
        hipLaunchKernelGGL((pass3_fix<float>), dim3(Cc * Hh), dim3(256), 0, stream,
                           rho, Ss, out);
    } else if (ws_size >= need * sizeof(__hip_bfloat16)) {
        __hip_bfloat16* ws  = (__hip_bfloat16*)d_ws;
        __hip_bfloat16* rho = ws;
        __hip_bfloat16* Mt  = ws + nTHN;
        __hip_bfloat16* Pt  = Mt + nCH;
        __hip_bfloat16* Ss  = Pt + nCH;
        hipLaunchKernelGGL((pass1_scan<__hip_bfloat16>), dim3(Cc * Hh), dim3(64), 0, stream,
                           r, w, k, v, a, b, yl, rho, Mt, Pt);
        hipLaunchKernelGGL((pass2_chain<__hip_bfloat16>), dim3(Hh * 8), dim3(256), 0, stream,
                           Mt, Pt, st, Ss, sfin);
        hipLaunchKernelGGL((pass3_fix<__hip_bfloat16>), dim3(Cc * Hh), dim3(256), 0, stream,
                           rho, Ss, out);
    } else {
        // no usable scratch: correct-but-slow sequential scan
        hipLaunchKernelGGL(seq_scan, dim3(Hh), dim3(64), 0, stream,
                           r, w, k, v, a, b, st, yl, sfin);
    }
}